// Round 15
// baseline (221.306 us; speedup 1.0000x reference)
//
#include <hip/hip_runtime.h>

#define BATCH 4
#define NS 4096
#define NA 1024
#define DIM 256
#define NH 8
#define HD 32

typedef float f32x4 __attribute__((ext_vector_type(4)));
typedef __bf16 bf16x8 __attribute__((ext_vector_type(8)));
typedef __bf16 bf16x2 __attribute__((ext_vector_type(2)));
typedef unsigned short u16x8 __attribute__((ext_vector_type(8)));
typedef unsigned short u16x4 __attribute__((ext_vector_type(4)));
typedef unsigned int u32x4 __attribute__((ext_vector_type(4)));
typedef unsigned int u32x2 __attribute__((ext_vector_type(2)));
typedef unsigned int u32;

__device__ inline unsigned short f2bf(float f) {
  unsigned int u = __builtin_bit_cast(unsigned int, f);
  u = (u + 0x7FFFu + ((u >> 16) & 1u)) >> 16;
  return (unsigned short)u;
}

__device__ inline float bf2f(unsigned short u) {
  return __builtin_bit_cast(float, ((unsigned int)u) << 16);
}

__device__ inline f32x4 ld_f4(const float* p) {
  return *reinterpret_cast<const f32x4*>(p);
}

__device__ inline bf16x8 cvt_bf8(f32x4 a, f32x4 b) {
  u16x8 r;
  r[0] = f2bf(a[0]); r[1] = f2bf(a[1]); r[2] = f2bf(a[2]); r[3] = f2bf(a[3]);
  r[4] = f2bf(b[0]); r[5] = f2bf(b[1]); r[6] = f2bf(b[2]); r[7] = f2bf(b[3]);
  return __builtin_bit_cast(bf16x8, r);
}

__device__ inline bf16x8 ld_bf8(const unsigned short* p) {
  return __builtin_bit_cast(bf16x8, *reinterpret_cast<const u32x4*>(p));
}

__device__ inline f32x4 mfma16(bf16x8 a, bf16x8 b, f32x4 c) {
  return __builtin_amdgcn_mfma_f32_16x16x32_bf16(a, b, c, 0, 0, 0);
}

__device__ inline u32 pack_bf2(float lo, float hi) {
  bf16x2 t;
  t[0] = (__bf16)lo;
  t[1] = (__bf16)hi;
  return __builtin_bit_cast(u32, t);
}

// Barrier that only drains LDS ops (lgkmcnt) — global stores stay in flight.
__device__ inline void bar_lgkm() {
  asm volatile("s_waitcnt lgkmcnt(0)" ::: "memory");
  asm volatile("s_barrier" ::: "memory");
}

// ---------------------------------------------------------------------------
// One-shot weight cast: 4 x (256x256) f32 -> bf16 in ws.
// ---------------------------------------------------------------------------
__global__ __launch_bounds__(256)
void cast_weights(const float* __restrict__ Wq, const float* __restrict__ Wk,
                  const float* __restrict__ Wv, const float* __restrict__ Wo,
                  unsigned short* __restrict__ out)
{
  const int i = blockIdx.x * 256 + threadIdx.x;
  const int seg = i >> 14, off = (i & 16383) * 4;
  const float* src = seg == 0 ? Wq : seg == 1 ? Wk : seg == 2 ? Wv : Wo;
  f32x4 v = ld_f4(src + off);
  u16x4 r;
  r[0] = f2bf(v[0]); r[1] = f2bf(v[1]); r[2] = f2bf(v[2]); r[3] = f2bf(v[3]);
  *reinterpret_cast<u16x4*>(out + (size_t)seg * 65536 + off) = r;
}

// ---------------------------------------------------------------------------
// Fused Q/K/V projection: 1536 blocks.
// ---------------------------------------------------------------------------
__global__ __launch_bounds__(256)
void proj_qkv_fused(const float* __restrict__ sat, const float* __restrict__ aux,
                    const unsigned short* __restrict__ Wb,
                    const float* __restrict__ bq, const float* __restrict__ bk,
                    const float* __restrict__ bv,
                    unsigned short* __restrict__ Qb, unsigned short* __restrict__ Kb,
                    unsigned short* __restrict__ Vt)
{
  __shared__ unsigned short T[16][264];
  const int bid = blockIdx.x;
  const float* X; const unsigned short* W; const float* bias;
  unsigned short* out; int Ntok, r0, mode;
  if (bid < 1024)      { X = sat; W = Wb;          bias = bq; out = Qb; Ntok = NS; r0 = bid * 16;          mode = 0; }
  else if (bid < 1280) { X = aux; W = Wb + 65536;  bias = bk; out = Kb; Ntok = NA; r0 = (bid - 1024) * 16; mode = 0; }
  else                 { X = aux; W = Wb + 131072; bias = bv; out = Vt; Ntok = NA; r0 = (bid - 1280) * 16; mode = 1; }

  const int tid = threadIdx.x;
  const int wave = tid >> 6, lane = tid & 63, g = lane >> 4, c = lane & 15;
  const int nb = wave * 64;

  f32x4 acc[4] = {};
#pragma unroll
  for (int ks = 0; ks < 8; ++ks) {
    const int k0 = ks * 32 + g * 8;
    const float* xp = X + (size_t)(r0 + c) * DIM + k0;
    bf16x8 af = cvt_bf8(ld_f4(xp), ld_f4(xp + 4));
#pragma unroll
    for (int nt = 0; nt < 4; ++nt) {
      bf16x8 bf = ld_bf8(W + (size_t)(nb + nt * 16 + c) * DIM + k0);
      acc[nt] = mfma16(af, bf, acc[nt]);
    }
  }
#pragma unroll
  for (int nt = 0; nt < 4; ++nt)
#pragma unroll
    for (int i = 0; i < 4; ++i) {
      const int n = nb + nt * 16 + c;
      T[g * 4 + i][n] = f2bf(acc[nt][i] + bias[n]);
    }
  __syncthreads();

  const int b = r0 / Ntok;
  const int t0 = r0 % Ntok;
  if (mode == 0) {
    const int h = tid >> 5, rem = tid & 31;
    const int row = rem >> 1, d0 = (rem & 1) * 16;
    u32x4 lo = *reinterpret_cast<const u32x4*>(&T[row][h * 32 + d0]);
    u32x4 hi = *reinterpret_cast<const u32x4*>(&T[row][h * 32 + d0 + 8]);
    unsigned short* op = out + ((size_t)(b * NH + h) * Ntok + t0 + row) * HD + d0;
    *reinterpret_cast<u32x4*>(op) = lo;
    *reinterpret_cast<u32x4*>(op + 8) = hi;
  } else {
    const int h = tid >> 5, d = tid & 31;
    u16x8 w0, w1;
#pragma unroll
    for (int r = 0; r < 8; ++r) {
      w0[r] = T[r][tid];
      w1[r] = T[8 + r][tid];
    }
    unsigned short* op = out + ((size_t)(b * NH + h) * HD + d) * NA + t0;
    *reinterpret_cast<u16x8*>(op) = w0;
    *reinterpret_cast<u16x8*>(op + 8) = w1;
  }
}

// ---------------------------------------------------------------------------
// Attention v14: v12 geometry (2048 blocks x 64 rows, 4 iters, load-free
// loop) with 3 RESIDENT BLOCKS/CU: single-buffered P_lds (LDS 38.4KB) +
// launch_bounds(256,3) (VGPR cap ~170; ~144 persistent). Third lgkm-only
// barrier at iter end protects single-buffer reuse (LDS reads complete
// into regs before it; global store drain stays off all barriers).
// ---------------------------------------------------------------------------
__global__ __launch_bounds__(256, 3)
void attn_kernel(const unsigned short* __restrict__ Qb,
                 const unsigned short* __restrict__ Kb,
                 const unsigned short* __restrict__ Vt,
                 float* __restrict__ attn_out,
                 unsigned short* __restrict__ attw)
{
  __shared__ unsigned short P_lds[4][16][264];     // e-values (single buf)
  __shared__ u32 attp2[4][16][17];
  __shared__ float wred[4][16];                    // e-sums

  // XCD swizzle: 2048 blocks -> 256-block contiguous chunk per XCD
  const int bid = blockIdx.x;
  const int blk = (bid & 7) * 256 + (bid >> 3);
  const int bh = blk >> 6;                  // 64 row-groups per (b,h)
  const int row0 = (blk & 63) << 6;         // 64 rows per block
  const int tid = threadIdx.x;
  const int wave = tid >> 6, lane = tid & 63, g = lane >> 4, c = lane & 15;
  const float expc = 0.17677669529663687f * 1.4426950408889634f; // scale*log2e

  const unsigned short* Kg = Kb + (size_t)bh * NA * HD;
  const unsigned short* Vg = Vt + (size_t)bh * HD * NA;
  const unsigned short* Qp = Qb + ((size_t)bh * NS + row0) * HD;
  const int ab = wave * 256;
  const int b = bh >> 3, h = bh & 7;

  // ---- preload K/V/Q slices into registers (the ONLY global loads) ----
  bf16x8 kfr[16], v0r[8], v1r[8], qfr[4];
#pragma unroll
  for (int nt = 0; nt < 16; ++nt)
    kfr[nt] = ld_bf8(Kg + (size_t)(ab + nt * 16 + c) * HD + g * 8);
#pragma unroll
  for (int ks = 0; ks < 8; ++ks) {
    v0r[ks] = ld_bf8(Vg + (size_t)c * NA + ab + ks * 32 + g * 8);
    v1r[ks] = ld_bf8(Vg + (size_t)(16 + c) * NA + ab + ks * 32 + g * 8);
  }
#pragma unroll
  for (int t = 0; t < 4; ++t)
    qfr[t] = ld_bf8(Qp + (size_t)(t * 16 + c) * HD + g * 8);

#pragma unroll
  for (int it = 0; it < 4; ++it) {
    const int s0 = row0 + it * 16;

    // QK^T (regs) + immediate exp + pack -> P_lds (acc transient per nt)
    float psum = 0.f;
#pragma unroll
    for (int nt = 0; nt < 16; ++nt) {
      f32x4 z = {0.f, 0.f, 0.f, 0.f};
      f32x4 a = mfma16(kfr[nt], qfr[it], z);
      float e0 = exp2f(a[0] * expc), e1 = exp2f(a[1] * expc);
      float e2 = exp2f(a[2] * expc), e3 = exp2f(a[3] * expc);
      psum += (e0 + e1) + (e2 + e3);
      u32x2 pk;
      pk[0] = pack_bf2(e0, e1);
      pk[1] = pack_bf2(e2, e3);
      *reinterpret_cast<u32x2*>(&P_lds[wave][c][nt * 16 + g * 4]) = pk;
    }
    psum += __shfl_xor(psum, 16);
    psum += __shfl_xor(psum, 32);
    if (lane < 16) wred[wave][lane] = psum;
    bar_lgkm();                               // B1 (lgkm only)

    // inv for this wave's PV output rows (g*4+i)
    float invo[4];
#pragma unroll
    for (int i = 0; i < 4; ++i) {
      const int r = g * 4 + i;
      invo[i] = 1.0f / (wred[0][r] + wred[1][r] + wred[2][r] + wred[3][r]);
    }

    // PV: P(e) from own LDS slice, V from regs
    f32x4 o0 = {}, o1 = {};
#pragma unroll
    for (int ks = 0; ks < 8; ++ks) {
      bf16x8 pf = ld_bf8(&P_lds[wave][c][ks * 32 + g * 8]);
      o0 = mfma16(pf, v0r[ks], o0);
      o1 = mfma16(pf, v1r[ks], o1);
    }
#pragma unroll
    for (int i = 0; i < 4; ++i)
      attp2[wave][g * 4 + i][c] = pack_bf2(o0[i] * invo[i], o1[i] * invo[i]);
    bar_lgkm();                               // B2 (publishes P_lds, attp2)

    // cross-wave attended reduce + attw write
#pragma unroll
    for (int t = tid; t < 512; t += 256) {
      const int row = t >> 5, col = t & 31;
      const int c2 = col & 15, hi2 = col >> 4;
      float s = 0.f;
#pragma unroll
      for (int w = 0; w < 4; ++w) {
        const u32 pk = attp2[w][row][c2];
        s += bf2f(hi2 ? (unsigned short)(pk >> 16) : (unsigned short)(pk & 0xffff));
      }
      attw[((size_t)b * NS + s0 + row) * DIM + h * HD + col] = f2bf(s);
    }

    // SEQUENTIAL P stream: wave w -> rows 4w..4w+3, all 1024 cols ascending,
    // normalized on the fly (invr uniform per row). Overlaps next iteration.
    float* aout = attn_out + ((size_t)bh * NS + s0) * NA;
#pragma unroll
    for (int rr = 0; rr < 4; ++rr) {
      const int row = wave * 4 + rr;
      const float invr = 1.0f / (wred[0][row] + wred[1][row] +
                                 wred[2][row] + wred[3][row]);
      float* rp = aout + (size_t)row * NA;
#pragma unroll
      for (int p = 0; p < 4; ++p) {
        u16x4 raw = *reinterpret_cast<const u16x4*>(&P_lds[p][row][lane * 4]);
        f32x4 o;
        o[0] = bf2f(raw[0]) * invr; o[1] = bf2f(raw[1]) * invr;
        o[2] = bf2f(raw[2]) * invr; o[3] = bf2f(raw[3]) * invr;
        *reinterpret_cast<f32x4*>(rp + p * 256 + lane * 4) = o;
      }
    }
    bar_lgkm();                               // B3: single-buffer reuse guard
                                              // (LDS reads above are done;
                                              // global stores keep draining)
  }
}

// ---------------------------------------------------------------------------
// Output projection + residual + LayerNorm, fused. Wo pre-cast bf16.
// ---------------------------------------------------------------------------
__global__ __launch_bounds__(256)
void out_proj_ln(const unsigned short* __restrict__ attw,
                 const float* __restrict__ sat,
                 const unsigned short* __restrict__ Wob, const float* __restrict__ bo,
                 const float* __restrict__ gamma, const float* __restrict__ beta,
                 float* __restrict__ out)
{
  __shared__ float Y[16][DIM];
  const int r0 = blockIdx.x * 16;
  const int tid = threadIdx.x;
  const int wave = tid >> 6, lane = tid & 63, g = lane >> 4, c = lane & 15;
  const int nb = wave * 64;

  f32x4 acc[4] = {};
#pragma unroll
  for (int ks = 0; ks < 8; ++ks) {
    const int k0 = ks * 32 + g * 8;
    bf16x8 af = ld_bf8(attw + (size_t)(r0 + c) * DIM + k0);
#pragma unroll
    for (int nt = 0; nt < 4; ++nt) {
      bf16x8 bf = ld_bf8(Wob + (size_t)(nb + nt * 16 + c) * DIM + k0);
      acc[nt] = mfma16(af, bf, acc[nt]);
    }
  }
#pragma unroll
  for (int nt = 0; nt < 4; ++nt)
#pragma unroll
    for (int i = 0; i < 4; ++i) {
      const int row = g * 4 + i, n = nb + nt * 16 + c;
      Y[row][n] = acc[nt][i] + bo[n] + sat[(size_t)(r0 + row) * DIM + n];
    }
  __syncthreads();

  const int row = tid >> 4, tt = tid & 15;
  f32x4 v[4];
  float s = 0.f, ss = 0.f;
#pragma unroll
  for (int j = 0; j < 4; ++j) {
    v[j] = *reinterpret_cast<const f32x4*>(&Y[row][tt * 4 + 64 * j]);
#pragma unroll
    for (int e = 0; e < 4; ++e) { s += v[j][e]; ss += v[j][e] * v[j][e]; }
  }
#pragma unroll
  for (int off = 1; off < 16; off <<= 1) {
    s += __shfl_xor(s, off);
    ss += __shfl_xor(ss, off);
  }
  const float mu = s * (1.0f / 256.0f);
  const float var = ss * (1.0f / 256.0f) - mu * mu;
  const float rstd = rsqrtf(var + 1e-5f);
  float* op = out + (size_t)(r0 + row) * DIM;
#pragma unroll
  for (int j = 0; j < 4; ++j) {
    const int n0 = tt * 4 + 64 * j;
    f32x4 r;
#pragma unroll
    for (int e = 0; e < 4; ++e)
      r[e] = (v[j][e] - mu) * rstd * gamma[n0 + e] + beta[n0 + e];
    *reinterpret_cast<f32x4*>(op + n0) = r;
  }
}

// ---------------------------------------------------------------------------
extern "C" void kernel_launch(void* const* d_in, const int* in_sizes, int n_in,
                              void* d_out, int out_size, void* d_ws, size_t ws_size,
                              hipStream_t stream)
{
  (void)in_sizes; (void)n_in; (void)out_size; (void)ws_size;
  const float* sat   = (const float*)d_in[0];
  const float* aux   = (const float*)d_in[1];
  const float* Wq    = (const float*)d_in[2];
  const float* bq    = (const float*)d_in[3];
  const float* Wk    = (const float*)d_in[4];
  const float* bk    = (const float*)d_in[5];
  const float* Wv    = (const float*)d_in[6];
  const float* bv    = (const float*)d_in[7];
  const float* Wo    = (const float*)d_in[8];
  const float* bo    = (const float*)d_in[9];
  const float* gamma = (const float*)d_in[10];
  const float* beta  = (const float*)d_in[11];

  float* out = (float*)d_out;                       // (B, NS, DIM) f32
  float* attn_out = out + (size_t)BATCH * NS * DIM; // (B, NH, NS, NA) f32

  // ws: Qb 8MB | Kb 2MB | Vt 2MB | attw 8MB | Wb(4x128KB) @20MB
  char* ws = (char*)d_ws;
  unsigned short* Qb   = (unsigned short*)(ws);
  unsigned short* Kb   = (unsigned short*)(ws + (8u << 20));
  unsigned short* Vt   = (unsigned short*)(ws + (10u << 20));
  unsigned short* attw = (unsigned short*)(ws + (12u << 20));
  unsigned short* Wb   = (unsigned short*)(ws + (20u << 20));
  unsigned short* Wob  = Wb + 3 * 65536;

  cast_weights<<<dim3(256), dim3(256), 0, stream>>>(Wq, Wk, Wv, Wo, Wb);
  proj_qkv_fused<<<dim3(1536), dim3(256), 0, stream>>>(sat, aux, Wb, bq, bk, bv, Qb, Kb, Vt);
  attn_kernel<<<dim3(2048), dim3(256), 0, stream>>>(Qb, Kb, Vt, attn_out, attw);
  out_proj_ln<<<dim3(BATCH * NS / 16), dim3(256), 0, stream>>>(attw, sat, Wob, bo, gamma, beta, out);
}

// Round 16
// 180.316 us; speedup vs baseline: 1.2273x; 1.2273x over previous
//
#include <hip/hip_runtime.h>

#define BATCH 4
#define NS 4096
#define NA 1024
#define DIM 256
#define NH 8
#define HD 32

typedef float f32x4 __attribute__((ext_vector_type(4)));
typedef __bf16 bf16x8 __attribute__((ext_vector_type(8)));
typedef __bf16 bf16x2 __attribute__((ext_vector_type(2)));
typedef unsigned short u16x8 __attribute__((ext_vector_type(8)));
typedef unsigned short u16x4 __attribute__((ext_vector_type(4)));
typedef unsigned int u32x4 __attribute__((ext_vector_type(4)));
typedef unsigned int u32x2 __attribute__((ext_vector_type(2)));
typedef unsigned int u32;

__device__ inline unsigned short f2bf(float f) {
  unsigned int u = __builtin_bit_cast(unsigned int, f);
  u = (u + 0x7FFFu + ((u >> 16) & 1u)) >> 16;
  return (unsigned short)u;
}

__device__ inline float bf2f(unsigned short u) {
  return __builtin_bit_cast(float, ((unsigned int)u) << 16);
}

__device__ inline f32x4 ld_f4(const float* p) {
  return *reinterpret_cast<const f32x4*>(p);
}

__device__ inline bf16x8 cvt_bf8(f32x4 a, f32x4 b) {
  u16x8 r;
  r[0] = f2bf(a[0]); r[1] = f2bf(a[1]); r[2] = f2bf(a[2]); r[3] = f2bf(a[3]);
  r[4] = f2bf(b[0]); r[5] = f2bf(b[1]); r[6] = f2bf(b[2]); r[7] = f2bf(b[3]);
  return __builtin_bit_cast(bf16x8, r);
}

__device__ inline bf16x8 ld_bf8(const unsigned short* p) {
  return __builtin_bit_cast(bf16x8, *reinterpret_cast<const u32x4*>(p));
}

__device__ inline f32x4 mfma16(bf16x8 a, bf16x8 b, f32x4 c) {
  return __builtin_amdgcn_mfma_f32_16x16x32_bf16(a, b, c, 0, 0, 0);
}

__device__ inline u32 pack_bf2(float lo, float hi) {
  bf16x2 t;
  t[0] = (__bf16)lo;
  t[1] = (__bf16)hi;
  return __builtin_bit_cast(u32, t);
}

// Barrier that only drains LDS ops (lgkmcnt) — global stores stay in flight.
__device__ inline void bar_lgkm() {
  asm volatile("s_waitcnt lgkmcnt(0)" ::: "memory");
  asm volatile("s_barrier" ::: "memory");
}

// ---------------------------------------------------------------------------
// One-shot weight cast: 4 x (256x256) f32 -> bf16 in ws.
// ---------------------------------------------------------------------------
__global__ __launch_bounds__(256)
void cast_weights(const float* __restrict__ Wq, const float* __restrict__ Wk,
                  const float* __restrict__ Wv, const float* __restrict__ Wo,
                  unsigned short* __restrict__ out)
{
  const int i = blockIdx.x * 256 + threadIdx.x;
  const int seg = i >> 14, off = (i & 16383) * 4;
  const float* src = seg == 0 ? Wq : seg == 1 ? Wk : seg == 2 ? Wv : Wo;
  f32x4 v = ld_f4(src + off);
  u16x4 r;
  r[0] = f2bf(v[0]); r[1] = f2bf(v[1]); r[2] = f2bf(v[2]); r[3] = f2bf(v[3]);
  *reinterpret_cast<u16x4*>(out + (size_t)seg * 65536 + off) = r;
}

// ---------------------------------------------------------------------------
// Fused Q/K/V projection: 1536 blocks.
// ---------------------------------------------------------------------------
__global__ __launch_bounds__(256)
void proj_qkv_fused(const float* __restrict__ sat, const float* __restrict__ aux,
                    const unsigned short* __restrict__ Wb,
                    const float* __restrict__ bq, const float* __restrict__ bk,
                    const float* __restrict__ bv,
                    unsigned short* __restrict__ Qb, unsigned short* __restrict__ Kb,
                    unsigned short* __restrict__ Vt)
{
  __shared__ unsigned short T[16][264];
  const int bid = blockIdx.x;
  const float* X; const unsigned short* W; const float* bias;
  unsigned short* out; int Ntok, r0, mode;
  if (bid < 1024)      { X = sat; W = Wb;          bias = bq; out = Qb; Ntok = NS; r0 = bid * 16;          mode = 0; }
  else if (bid < 1280) { X = aux; W = Wb + 65536;  bias = bk; out = Kb; Ntok = NA; r0 = (bid - 1024) * 16; mode = 0; }
  else                 { X = aux; W = Wb + 131072; bias = bv; out = Vt; Ntok = NA; r0 = (bid - 1280) * 16; mode = 1; }

  const int tid = threadIdx.x;
  const int wave = tid >> 6, lane = tid & 63, g = lane >> 4, c = lane & 15;
  const int nb = wave * 64;

  f32x4 acc[4] = {};
#pragma unroll
  for (int ks = 0; ks < 8; ++ks) {
    const int k0 = ks * 32 + g * 8;
    const float* xp = X + (size_t)(r0 + c) * DIM + k0;
    bf16x8 af = cvt_bf8(ld_f4(xp), ld_f4(xp + 4));
#pragma unroll
    for (int nt = 0; nt < 4; ++nt) {
      bf16x8 bf = ld_bf8(W + (size_t)(nb + nt * 16 + c) * DIM + k0);
      acc[nt] = mfma16(af, bf, acc[nt]);
    }
  }
#pragma unroll
  for (int nt = 0; nt < 4; ++nt)
#pragma unroll
    for (int i = 0; i < 4; ++i) {
      const int n = nb + nt * 16 + c;
      T[g * 4 + i][n] = f2bf(acc[nt][i] + bias[n]);
    }
  __syncthreads();

  const int b = r0 / Ntok;
  const int t0 = r0 % Ntok;
  if (mode == 0) {
    const int h = tid >> 5, rem = tid & 31;
    const int row = rem >> 1, d0 = (rem & 1) * 16;
    u32x4 lo = *reinterpret_cast<const u32x4*>(&T[row][h * 32 + d0]);
    u32x4 hi = *reinterpret_cast<const u32x4*>(&T[row][h * 32 + d0 + 8]);
    unsigned short* op = out + ((size_t)(b * NH + h) * Ntok + t0 + row) * HD + d0;
    *reinterpret_cast<u32x4*>(op) = lo;
    *reinterpret_cast<u32x4*>(op + 8) = hi;
  } else {
    const int h = tid >> 5, d = tid & 31;
    u16x8 w0, w1;
#pragma unroll
    for (int r = 0; r < 8; ++r) {
      w0[r] = T[r][tid];
      w1[r] = T[8 + r][tid];
    }
    unsigned short* op = out + ((size_t)(b * NH + h) * HD + d) * NA + t0;
    *reinterpret_cast<u16x8*>(op) = w0;
    *reinterpret_cast<u16x8*>(op + 8) = w1;
  }
}

// ---------------------------------------------------------------------------
// Attention v12 (session best, 180.9us): 2048 blocks, each = one (b,h) x
// 64 rows (4 iterations). K/V/Q preloaded into registers (~145 VGPR
// persistent) -> loop has ZERO global loads (no waitcnt couples to the
// P-store stream). P (raw e, bf16) double-buffered in LDS; inv folded into
// PV epilogue + store path; lgkm-only barriers. 8 blocks/CU total work
// (2 resident, staggered).
// ---------------------------------------------------------------------------
__global__ __launch_bounds__(256, 2)
void attn_kernel(const unsigned short* __restrict__ Qb,
                 const unsigned short* __restrict__ Kb,
                 const unsigned short* __restrict__ Vt,
                 float* __restrict__ attn_out,
                 unsigned short* __restrict__ attw)
{
  __shared__ unsigned short P_lds[2][4][16][264];  // e-values, dbuf
  __shared__ u32 attp2[4][16][17];
  __shared__ float wred[2][4][16];                 // e-sums, dbuf

  // XCD swizzle: 2048 blocks -> 256-block contiguous chunk per XCD
  const int bid = blockIdx.x;
  const int blk = (bid & 7) * 256 + (bid >> 3);
  const int bh = blk >> 6;                  // 64 row-groups per (b,h)
  const int row0 = (blk & 63) << 6;         // 64 rows per block
  const int tid = threadIdx.x;
  const int wave = tid >> 6, lane = tid & 63, g = lane >> 4, c = lane & 15;
  const float expc = 0.17677669529663687f * 1.4426950408889634f; // scale*log2e

  const unsigned short* Kg = Kb + (size_t)bh * NA * HD;
  const unsigned short* Vg = Vt + (size_t)bh * HD * NA;
  const unsigned short* Qp = Qb + ((size_t)bh * NS + row0) * HD;
  const int ab = wave * 256;
  const int b = bh >> 3, h = bh & 7;

  // ---- preload K/V/Q slices into registers (the ONLY global loads) ----
  bf16x8 kfr[16], v0r[8], v1r[8], qfr[4];
#pragma unroll
  for (int nt = 0; nt < 16; ++nt)
    kfr[nt] = ld_bf8(Kg + (size_t)(ab + nt * 16 + c) * HD + g * 8);
#pragma unroll
  for (int ks = 0; ks < 8; ++ks) {
    v0r[ks] = ld_bf8(Vg + (size_t)c * NA + ab + ks * 32 + g * 8);
    v1r[ks] = ld_bf8(Vg + (size_t)(16 + c) * NA + ab + ks * 32 + g * 8);
  }
#pragma unroll
  for (int t = 0; t < 4; ++t)
    qfr[t] = ld_bf8(Qp + (size_t)(t * 16 + c) * HD + g * 8);

#pragma unroll
  for (int it = 0; it < 4; ++it) {
    const int pb = it & 1;
    const int s0 = row0 + it * 16;

    // QK^T (regs) + immediate exp + pack -> P_lds (acc transient per nt)
    float psum = 0.f;
#pragma unroll
    for (int nt = 0; nt < 16; ++nt) {
      f32x4 z = {0.f, 0.f, 0.f, 0.f};
      f32x4 a = mfma16(kfr[nt], qfr[it], z);
      float e0 = exp2f(a[0] * expc), e1 = exp2f(a[1] * expc);
      float e2 = exp2f(a[2] * expc), e3 = exp2f(a[3] * expc);
      psum += (e0 + e1) + (e2 + e3);
      u32x2 pk;
      pk[0] = pack_bf2(e0, e1);
      pk[1] = pack_bf2(e2, e3);
      *reinterpret_cast<u32x2*>(&P_lds[pb][wave][c][nt * 16 + g * 4]) = pk;
    }
    psum += __shfl_xor(psum, 16);
    psum += __shfl_xor(psum, 32);
    if (lane < 16) wred[pb][wave][lane] = psum;
    bar_lgkm();                               // B1 (lgkm only)

    // inv for this wave's PV output rows (g*4+i)
    float invo[4];
#pragma unroll
    for (int i = 0; i < 4; ++i) {
      const int r = g * 4 + i;
      invo[i] = 1.0f / (wred[pb][0][r] + wred[pb][1][r] +
                        wred[pb][2][r] + wred[pb][3][r]);
    }

    // PV: P(e) from own LDS slice, V from regs
    f32x4 o0 = {}, o1 = {};
#pragma unroll
    for (int ks = 0; ks < 8; ++ks) {
      bf16x8 pf = ld_bf8(&P_lds[pb][wave][c][ks * 32 + g * 8]);
      o0 = mfma16(pf, v0r[ks], o0);
      o1 = mfma16(pf, v1r[ks], o1);
    }
#pragma unroll
    for (int i = 0; i < 4; ++i)
      attp2[wave][g * 4 + i][c] = pack_bf2(o0[i] * invo[i], o1[i] * invo[i]);
    bar_lgkm();                               // B2 (publishes P_lds, attp2)

    // cross-wave attended reduce + attw write
#pragma unroll
    for (int t = tid; t < 512; t += 256) {
      const int row = t >> 5, col = t & 31;
      const int c2 = col & 15, hi2 = col >> 4;
      float s = 0.f;
#pragma unroll
      for (int w = 0; w < 4; ++w) {
        const u32 pk = attp2[w][row][c2];
        s += bf2f(hi2 ? (unsigned short)(pk >> 16) : (unsigned short)(pk & 0xffff));
      }
      attw[((size_t)b * NS + s0 + row) * DIM + h * HD + col] = f2bf(s);
    }

    // SEQUENTIAL P stream: wave w -> rows 4w..4w+3, all 1024 cols ascending,
    // normalized on the fly (invr uniform per row). Overlaps next iteration.
    float* aout = attn_out + ((size_t)bh * NS + s0) * NA;
#pragma unroll
    for (int rr = 0; rr < 4; ++rr) {
      const int row = wave * 4 + rr;
      const float invr = 1.0f / (wred[pb][0][row] + wred[pb][1][row] +
                                 wred[pb][2][row] + wred[pb][3][row]);
      float* rp = aout + (size_t)row * NA;
#pragma unroll
      for (int p = 0; p < 4; ++p) {
        u16x4 raw = *reinterpret_cast<const u16x4*>(&P_lds[pb][p][row][lane * 4]);
        f32x4 o;
        o[0] = bf2f(raw[0]) * invr; o[1] = bf2f(raw[1]) * invr;
        o[2] = bf2f(raw[2]) * invr; o[3] = bf2f(raw[3]) * invr;
        *reinterpret_cast<f32x4*>(rp + p * 256 + lane * 4) = o;
      }
    }
  }
}

// ---------------------------------------------------------------------------
// Output projection + residual + LayerNorm, fused. Wo pre-cast bf16.
// ---------------------------------------------------------------------------
__global__ __launch_bounds__(256)
void out_proj_ln(const unsigned short* __restrict__ attw,
                 const float* __restrict__ sat,
                 const unsigned short* __restrict__ Wob, const float* __restrict__ bo,
                 const float* __restrict__ gamma, const float* __restrict__ beta,
                 float* __restrict__ out)
{
  __shared__ float Y[16][DIM];
  const int r0 = blockIdx.x * 16;
  const int tid = threadIdx.x;
  const int wave = tid >> 6, lane = tid & 63, g = lane >> 4, c = lane & 15;
  const int nb = wave * 64;

  f32x4 acc[4] = {};
#pragma unroll
  for (int ks = 0; ks < 8; ++ks) {
    const int k0 = ks * 32 + g * 8;
    bf16x8 af = ld_bf8(attw + (size_t)(r0 + c) * DIM + k0);
#pragma unroll
    for (int nt = 0; nt < 4; ++nt) {
      bf16x8 bf = ld_bf8(Wob + (size_t)(nb + nt * 16 + c) * DIM + k0);
      acc[nt] = mfma16(af, bf, acc[nt]);
    }
  }
#pragma unroll
  for (int nt = 0; nt < 4; ++nt)
#pragma unroll
    for (int i = 0; i < 4; ++i) {
      const int row = g * 4 + i, n = nb + nt * 16 + c;
      Y[row][n] = acc[nt][i] + bo[n] + sat[(size_t)(r0 + row) * DIM + n];
    }
  __syncthreads();

  const int row = tid >> 4, tt = tid & 15;
  f32x4 v[4];
  float s = 0.f, ss = 0.f;
#pragma unroll
  for (int j = 0; j < 4; ++j) {
    v[j] = *reinterpret_cast<const f32x4*>(&Y[row][tt * 4 + 64 * j]);
#pragma unroll
    for (int e = 0; e < 4; ++e) { s += v[j][e]; ss += v[j][e] * v[j][e]; }
  }
#pragma unroll
  for (int off = 1; off < 16; off <<= 1) {
    s += __shfl_xor(s, off);
    ss += __shfl_xor(ss, off);
  }
  const float mu = s * (1.0f / 256.0f);
  const float var = ss * (1.0f / 256.0f) - mu * mu;
  const float rstd = rsqrtf(var + 1e-5f);
  float* op = out + (size_t)(r0 + row) * DIM;
#pragma unroll
  for (int j = 0; j < 4; ++j) {
    const int n0 = tt * 4 + 64 * j;
    f32x4 r;
#pragma unroll
    for (int e = 0; e < 4; ++e)
      r[e] = (v[j][e] - mu) * rstd * gamma[n0 + e] + beta[n0 + e];
    *reinterpret_cast<f32x4*>(op + n0) = r;
  }
}

// ---------------------------------------------------------------------------
extern "C" void kernel_launch(void* const* d_in, const int* in_sizes, int n_in,
                              void* d_out, int out_size, void* d_ws, size_t ws_size,
                              hipStream_t stream)
{
  (void)in_sizes; (void)n_in; (void)out_size; (void)ws_size;
  const float* sat   = (const float*)d_in[0];
  const float* aux   = (const float*)d_in[1];
  const float* Wq    = (const float*)d_in[2];
  const float* bq    = (const float*)d_in[3];
  const float* Wk    = (const float*)d_in[4];
  const float* bk    = (const float*)d_in[5];
  const float* Wv    = (const float*)d_in[6];
  const float* bv    = (const float*)d_in[7];
  const float* Wo    = (const float*)d_in[8];
  const float* bo    = (const float*)d_in[9];
  const float* gamma = (const float*)d_in[10];
  const float* beta  = (const float*)d_in[11];

  float* out = (float*)d_out;                       // (B, NS, DIM) f32
  float* attn_out = out + (size_t)BATCH * NS * DIM; // (B, NH, NS, NA) f32

  // ws: Qb 8MB | Kb 2MB | Vt 2MB | attw 8MB | Wb(4x128KB) @20MB
  char* ws = (char*)d_ws;
  unsigned short* Qb   = (unsigned short*)(ws);
  unsigned short* Kb   = (unsigned short*)(ws + (8u << 20));
  unsigned short* Vt   = (unsigned short*)(ws + (10u << 20));
  unsigned short* attw = (unsigned short*)(ws + (12u << 20));
  unsigned short* Wb   = (unsigned short*)(ws + (20u << 20));
  unsigned short* Wob  = Wb + 3 * 65536;

  cast_weights<<<dim3(256), dim3(256), 0, stream>>>(Wq, Wk, Wv, Wo, Wb);
  proj_qkv_fused<<<dim3(1536), dim3(256), 0, stream>>>(sat, aux, Wb, bq, bk, bv, Qb, Kb, Vt);
  attn_kernel<<<dim3(2048), dim3(256), 0, stream>>>(Qb, Kb, Vt, attn_out, attw);
  out_proj_ln<<<dim3(BATCH * NS / 16), dim3(256), 0, stream>>>(attw, sat, Wob, bo, gamma, beta, out);
}